// Round 20
// baseline (407.794 us; speedup 1.0000x reference)
//
#include <hip/hip_runtime.h>

#define BS 256
#define LD4(ptr) (*reinterpret_cast<const float4*>(ptr))

__device__ __forceinline__ float fast_acos(float x) {
    // Abramowitz & Stegun 4.4.45; raw v_sqrt (arg in [0,1]).
    // |err| <= ~6.8e-5 rad; output weight 0.002 -> contribution <= 2e-7.
    float ax = fabsf(x);
    float s  = __builtin_amdgcn_sqrtf(fmaxf(0.f, 1.f - ax));
    float p  = fmaf(ax, fmaf(ax, fmaf(ax, -0.0187293f, 0.0742610f), -0.2121144f), 1.5707288f);
    float r  = s * p;
    return (x >= 0.f) ? r : 3.14159265358979f - r;
}

__device__ __forceinline__ float ang(float p2, float t2, float dot) {
    float inv = __builtin_amdgcn_rsqf(p2 * t2);   // raw v_rsq: 1 instr
    float c   = __builtin_amdgcn_fmed3f(dot * inv, -1.f, 1.f);
    return fast_acos(c);
}

// Shared-subexpression corner math (r19): 8 diffs, 8 squares, 4 cross-products
// computed once; each box corner is 3 adds + ang().
__device__ __forceinline__ float dir_item(float4 L, float4 O, float4 Tn, bool first) {
    float pa = L.x + O.x, pb = L.y + O.y;
    float Px0 = pa - 0.5f * (L.z + O.z), Py0 = pb - 0.5f * (L.w + O.w);
    float Px1 = pa, Py1 = pb;
    float Tx0 = Tn.x - 0.5f * Tn.z, Ty0 = Tn.y - 0.5f * Tn.w;
    float Tx1 = Tn.x, Ty1 = Tn.y;
    float Lx1 = L.x - 0.5f * L.z, Ly1 = L.y - 0.5f * L.w;
    float Lx0, Ly0;
    if (first) { Lx0 = Lx1; Ly0 = Ly1; Lx1 = L.x; Ly1 = L.y; }
    else       { Lx0 = 0.5f * (L.x - L.z); Ly0 = 0.5f * (L.y - L.w); }

    float ax0 = Px0 - Lx0, ax1 = Px1 - Lx1, ay0 = Py0 - Ly0, ay1 = Py1 - Ly1;
    float bx0 = Tx0 - Lx0, bx1 = Tx1 - Lx1, by0 = Ty0 - Ly0, by1 = Ty1 - Ly1;
    float acx = 0.5f * (ax0 + ax1), acy = 0.5f * (ay0 + ay1);
    float bcx = 0.5f * (bx0 + bx1), bcy = 0.5f * (by0 + by1);
    float sax0 = ax0 * ax0, sax1 = ax1 * ax1, say0 = ay0 * ay0, say1 = ay1 * ay1;
    float sbx0 = bx0 * bx0, sbx1 = bx1 * bx1, sby0 = by0 * by0, sby1 = by1 * by1;
    float cx0 = ax0 * bx0, cx1 = ax1 * bx1, cy0 = ay0 * by0, cy1 = ay1 * by1;

    float acc;
    acc  = ang(fmaf(acx, acx, acy * acy), fmaf(bcx, bcx, bcy * bcy),
               fmaf(acx, bcx, acy * bcy));
    acc += ang(sax0 + say0, sbx0 + sby0, cx0 + cy0);
    acc += ang(sax0 + say1, sbx0 + sby1, cx0 + cy1);
    acc += ang(sax1 + say0, sbx1 + sby0, cx1 + cy0);
    acc += ang(sax1 + say1, sbx1 + sby1, cx1 + cy1);
    return acc;
}

__device__ __forceinline__ float sl1_4(float4 O, float4 D) {
    float s = 0.f;
    { float d = O.x - D.x, ad = fabsf(d); s += (ad < 1.f) ? 0.5f * d * d : ad - 0.5f; }
    { float d = O.y - D.y, ad = fabsf(d); s += (ad < 1.f) ? 0.5f * d * d : ad - 0.5f; }
    { float d = O.z - D.z, ad = fabsf(d); s += (ad < 1.f) ? 0.5f * d * d : ad - 0.5f; }
    { float d = O.w - D.w, ad = fabsf(d); s += (ad < 1.f) ? 0.5f * d * d : ad - 0.5f; }
    return s;
}

// Single kernel. Phase 1 writes sl1*w to out BEFORE the barrier (no state held
// across it -> no spills, r16's failure mode). Software grid barrier (agent
// atomics; G=2040 < 2048 co-residency capacity at launch_bounds(256,8)).
// Phase 2 is producer-matched: each thread RMWs exactly the bytes it wrote ->
// same XCD L2 (coherent + warm). Counter memset per launch -> deterministic.
__global__ __launch_bounds__(BS, 8)
void fused_all(const float* __restrict__ outputs,
               const float* __restrict__ targets,
               float* __restrict__ out,
               float* __restrict__ partials,
               unsigned int* __restrict__ counter,
               int P, float w, int G) {
    __shared__ float  smem[BS / 64];
    __shared__ double dsm[BS / 64];
    __shared__ float  c_sh;
    const long long total = 4ll * P;
    const long long NT = (long long)G * BS;
    long long gid = (long long)blockIdx.x * BS + threadIdx.x;

    // ---- phase 1: dir partials + sl1 written immediately ----
    float acc = 0.f;
    for (long long u = gid; u < total; u += NT) {
        int grp     = (int)(u / P);
        long long p = u - (long long)grp * P;
        const long long ts8 = 8ll * P, os4 = 4ll * P;
        const float* tb = targets + ((long long)(grp * 4) * P + p) * 8;
        const float* ob = outputs + ((long long)(grp * 4) * P + p) * 4;
        float*       wb = out + (long long)(grp * 4) * P + p;
        const bool has4 = (grp < 3);

        float4 Tf0 = LD4(tb);
        float4 Tf1 = LD4(tb + ts8);
        float4 Tf2 = LD4(tb + 2 * ts8);
        float4 Tf3 = LD4(tb + 3 * ts8);
        float4 Ts0 = LD4(tb + 4);
        float4 Ts1 = LD4(tb + ts8 + 4);
        float4 Ts2 = LD4(tb + 2 * ts8 + 4);
        float4 Ts3 = LD4(tb + 3 * ts8 + 4);
        float4 O0  = LD4(ob);
        float4 O1  = LD4(ob + os4);
        float4 O2  = LD4(ob + 2 * os4);
        float4 O3  = LD4(ob + 3 * os4);
        float4 Tf4 = has4 ? LD4(tb + 4 * ts8) : make_float4(0.f, 0.f, 0.f, 0.f);

        wb[0]       = sl1_4(O0, Ts0) * w;
        wb[P]       = sl1_4(O1, Ts1) * w;
        wb[2ll * P] = sl1_4(O2, Ts2) * w;
        wb[3ll * P] = sl1_4(O3, Ts3) * w;

        acc += dir_item(Tf0, O0, Tf1, grp == 0);
        acc += dir_item(Tf1, O1, Tf2, false);
        acc += dir_item(Tf2, O2, Tf3, false);
        if (has4) acc += dir_item(Tf3, O3, Tf4, false);
    }

    #pragma unroll
    for (int off = 32; off > 0; off >>= 1) acc += __shfl_down(acc, off, 64);
    int lane = threadIdx.x & 63, wv = threadIdx.x >> 6;
    if (lane == 0) smem[wv] = acc;
    __syncthreads();

    // ---- software grid barrier (no live VGPR state crosses it) ----
    if (threadIdx.x == 0) {
        float r = smem[0] + smem[1] + smem[2] + smem[3];
        __hip_atomic_store(&partials[blockIdx.x], r, __ATOMIC_RELEASE,
                           __HIP_MEMORY_SCOPE_AGENT);
        unsigned int done = __hip_atomic_fetch_add(counter, 1u, __ATOMIC_ACQ_REL,
                                                   __HIP_MEMORY_SCOPE_AGENT) + 1u;
        if (done < (unsigned int)G) {
            while (__hip_atomic_load(counter, __ATOMIC_ACQUIRE,
                                     __HIP_MEMORY_SCOPE_AGENT) < (unsigned int)G)
                __builtin_amdgcn_s_sleep(2);
        }
    }
    __syncthreads();

    // ---- every block reduces the G partials (8 KB, L2-resident) ----
    double dacc = 0.0;
    for (int i = threadIdx.x; i < G; i += BS)
        dacc += (double)__hip_atomic_load(&partials[i], __ATOMIC_RELAXED,
                                          __HIP_MEMORY_SCOPE_AGENT);
    #pragma unroll
    for (int off = 32; off > 0; off >>= 1) dacc += __shfl_down(dacc, off, 64);
    if (lane == 0) dsm[wv] = dacc;
    __syncthreads();
    if (threadIdx.x == 0) {
        double tot = dsm[0] + dsm[1] + dsm[2] + dsm[3];
        c_sh = (float)(0.01 * 0.2 * tot / ((double)P * 15.0));
    }
    __syncthreads();
    float c = c_sh;

    // ---- phase 2: producer-matched += c (same lines this thread wrote) ----
    for (long long u = gid; u < total; u += NT) {
        int grp     = (int)(u / P);
        long long p = u - (long long)grp * P;
        float* wb = out + (long long)(grp * 4) * P + p;
        wb[0]       += c;
        wb[P]       += c;
        wb[2ll * P] += c;
        wb[3ll * P] += c;
    }
}

extern "C" void kernel_launch(void* const* d_in, const int* in_sizes, int n_in,
                              void* d_out, int out_size, void* d_ws, size_t ws_size,
                              hipStream_t stream) {
    const float* outputs = (const float*)d_in[0];
    const float* targets = (const float*)d_in[1];
    float* out = (float*)d_out;
    float* partials = (float*)d_ws;                         // G floats
    unsigned int* counter = (unsigned int*)(partials + 2048);

    const int T = 16;
    int P = in_sizes[0] / (T * 4);                          // 200000
    const int G = 2040;                                     // < 2048 co-residency cap

    hipMemsetAsync(counter, 0, sizeof(unsigned int), stream);
    fused_all<<<G, BS, 0, stream>>>(outputs, targets, out, partials, counter,
                                    P, 0.99f / (float)P, G);
}

// Round 23
// 60.950 us; speedup vs baseline: 6.6906x; 6.6906x over previous
//
#include <hip/hip_runtime.h>

#define BS 256
#define LD4(ptr) (*reinterpret_cast<const float4*>(ptr))

__device__ __forceinline__ float fast_acos(float x) {
    // Abramowitz & Stegun 4.4.45; raw v_sqrt (arg in [0,1]).
    // |err| <= ~6.8e-5 rad; output weight 0.002 -> contribution <= 2e-7.
    float ax = fabsf(x);
    float s  = __builtin_amdgcn_sqrtf(fmaxf(0.f, 1.f - ax));
    float p  = fmaf(ax, fmaf(ax, fmaf(ax, -0.0187293f, 0.0742610f), -0.2121144f), 1.5707288f);
    float r  = s * p;
    return (x >= 0.f) ? r : 3.14159265358979f - r;
}

__device__ __forceinline__ float ang(float p2, float t2, float dot) {
    float inv = __builtin_amdgcn_rsqf(p2 * t2);   // raw v_rsq: 1 instr
    float c   = __builtin_amdgcn_fmed3f(dot * inv, -1.f, 1.f);
    return fast_acos(c);
}

// Shared-subexpression corner math (r19-verified).
__device__ __forceinline__ float dir_item(float4 L, float4 O, float4 Tn, bool first) {
    float pa = L.x + O.x, pb = L.y + O.y;
    float Px0 = pa - 0.5f * (L.z + O.z), Py0 = pb - 0.5f * (L.w + O.w);
    float Px1 = pa, Py1 = pb;
    float Tx0 = Tn.x - 0.5f * Tn.z, Ty0 = Tn.y - 0.5f * Tn.w;
    float Tx1 = Tn.x, Ty1 = Tn.y;
    float Lx1 = L.x - 0.5f * L.z, Ly1 = L.y - 0.5f * L.w;
    float Lx0, Ly0;
    if (first) { Lx0 = Lx1; Ly0 = Ly1; Lx1 = L.x; Ly1 = L.y; }
    else       { Lx0 = 0.5f * (L.x - L.z); Ly0 = 0.5f * (L.y - L.w); }

    float ax0 = Px0 - Lx0, ax1 = Px1 - Lx1, ay0 = Py0 - Ly0, ay1 = Py1 - Ly1;
    float bx0 = Tx0 - Lx0, bx1 = Tx1 - Lx1, by0 = Ty0 - Ly0, by1 = Ty1 - Ly1;
    float acx = 0.5f * (ax0 + ax1), acy = 0.5f * (ay0 + ay1);
    float bcx = 0.5f * (bx0 + bx1), bcy = 0.5f * (by0 + by1);
    float sax0 = ax0 * ax0, sax1 = ax1 * ax1, say0 = ay0 * ay0, say1 = ay1 * ay1;
    float sbx0 = bx0 * bx0, sbx1 = bx1 * bx1, sby0 = by0 * by0, sby1 = by1 * by1;
    float cx0 = ax0 * bx0, cx1 = ax1 * bx1, cy0 = ay0 * by0, cy1 = ay1 * by1;

    float acc;
    acc  = ang(fmaf(acx, acx, acy * acy), fmaf(bcx, bcx, bcy * bcy),
               fmaf(acx, bcx, acy * bcy));
    acc += ang(sax0 + say0, sbx0 + sby0, cx0 + cy0);
    acc += ang(sax0 + say1, sbx0 + sby1, cx0 + cy1);
    acc += ang(sax1 + say0, sbx1 + sby0, cx1 + cy0);
    acc += ang(sax1 + say1, sbx1 + sby1, cx1 + cy1);
    return acc;
}

// DIR-ONLY kernel: 9 VMEM instructions per thread (was 17 with sl1 fused).
// One thread per (p, t-quarter): loads 5 targets-first-halves + 4 outputs.
__global__ __launch_bounds__(BS)
void dir_kernel(const float* __restrict__ outputs,
                const float* __restrict__ targets,
                float* __restrict__ partials,
                int P) {
    __shared__ float smem[BS / 64];
    long long gid = (long long)blockIdx.x * BS + threadIdx.x;
    float acc = 0.f;
    if (gid < 4ll * P) {
        int grp     = (int)(gid / P);          // 0..3
        long long p = gid - (long long)grp * P;
        const long long ts8 = 8ll * P, os4 = 4ll * P;
        const float* tb = targets + ((long long)(grp * 4) * P + p) * 8;
        const float* ob = outputs + ((long long)(grp * 4) * P + p) * 4;
        const bool has4 = (grp < 3);

        float4 Tf0 = LD4(tb);
        float4 Tf1 = LD4(tb + ts8);
        float4 Tf2 = LD4(tb + 2 * ts8);
        float4 Tf3 = LD4(tb + 3 * ts8);
        float4 O0  = LD4(ob);
        float4 O1  = LD4(ob + os4);
        float4 O2  = LD4(ob + 2 * os4);
        float4 O3  = LD4(ob + 3 * os4);
        float4 Tf4 = has4 ? LD4(tb + 4 * ts8) : make_float4(0.f, 0.f, 0.f, 0.f);

        acc  = dir_item(Tf0, O0, Tf1, grp == 0);
        acc += dir_item(Tf1, O1, Tf2, false);
        acc += dir_item(Tf2, O2, Tf3, false);
        if (has4) acc += dir_item(Tf3, O3, Tf4, false);
    }
    #pragma unroll
    for (int off = 32; off > 0; off >>= 1) acc += __shfl_down(acc, off, 64);
    int lane = threadIdx.x & 63, w64 = threadIdx.x >> 6;
    if (lane == 0) smem[w64] = acc;
    __syncthreads();
    if (threadIdx.x == 0) {
        float r = 0.f;
        #pragma unroll
        for (int i = 0; i < BS / 64; ++i) r += smem[i];
        partials[blockIdx.x] = r;
    }
}

// sl1 + constant, fully coalesced (round-7 out_kernel shape, ~14 TB/s warm):
// per out element = 2 float4 loads + 1 scalar store, lane-contiguous.
__global__ __launch_bounds__(BS)
void out_kernel(const float* __restrict__ outputs,
                const float* __restrict__ targets,
                const float* __restrict__ partials, int nb,
                float* __restrict__ out,
                long long n, int P, float w) {
    __shared__ double dsm[BS / 64];
    __shared__ float c_sh;
    double dacc = 0.0;
    for (int i = threadIdx.x; i < nb; i += BS) dacc += (double)partials[i];
    #pragma unroll
    for (int off = 32; off > 0; off >>= 1) dacc += __shfl_down(dacc, off, 64);
    int lane = threadIdx.x & 63, wv = threadIdx.x >> 6;
    if (lane == 0) dsm[wv] = dacc;
    __syncthreads();
    if (threadIdx.x == 0) {
        double tot = dsm[0] + dsm[1] + dsm[2] + dsm[3];
        c_sh = (float)(0.01 * 0.2 * tot / ((double)P * 15.0));
    }
    __syncthreads();
    float c = c_sh;

    long long stride = (long long)gridDim.x * blockDim.x;
    for (long long i = (long long)blockIdx.x * blockDim.x + threadIdx.x; i < n; i += stride) {
        const float4 O = LD4(outputs + i * 4);
        const float4 D = LD4(targets + i * 8 + 4);
        float s = 0.f;
        { float d = O.x - D.x, ad = fabsf(d); s += (ad < 1.f) ? 0.5f * d * d : ad - 0.5f; }
        { float d = O.y - D.y, ad = fabsf(d); s += (ad < 1.f) ? 0.5f * d * d : ad - 0.5f; }
        { float d = O.z - D.z, ad = fabsf(d); s += (ad < 1.f) ? 0.5f * d * d : ad - 0.5f; }
        { float d = O.w - D.w, ad = fabsf(d); s += (ad < 1.f) ? 0.5f * d * d : ad - 0.5f; }
        out[i] = fmaf(s, w, c);
    }
}

extern "C" void kernel_launch(void* const* d_in, const int* in_sizes, int n_in,
                              void* d_out, int out_size, void* d_ws, size_t ws_size,
                              hipStream_t stream) {
    const float* outputs = (const float*)d_in[0];
    const float* targets = (const float*)d_in[1];
    float* out = (float*)d_out;
    float* partials = (float*)d_ws;

    const int T = 16;
    int P = in_sizes[0] / (T * 4);                 // 200000

    long long units = 4ll * P;                     // 800,000
    int nb1 = (int)((units + BS - 1) / BS);        // 3125 blocks
    dir_kernel<<<nb1, BS, 0, stream>>>(outputs, targets, partials, P);

    long long n = (long long)out_size;             // 16P scalar outputs
    int nb2 = (int)((n + BS - 1) / BS);
    if (nb2 > 3125) nb2 = 3125;
    out_kernel<<<nb2, BS, 0, stream>>>(outputs, targets, partials, nb1, out, n, P,
                                       0.99f / (float)P);
}

// Round 24
// 42.717 us; speedup vs baseline: 9.5464x; 1.4268x over previous
//
#include <hip/hip_runtime.h>

#define BS 256
#define LD4(ptr) (*reinterpret_cast<const float4*>(ptr))

__device__ __forceinline__ float fast_acos(float x) {
    // Abramowitz & Stegun 4.4.45; raw v_sqrt (arg in [0,1]).
    // |err| <= ~6.8e-5 rad; output weight 0.002 -> contribution <= 2e-7.
    float ax = fabsf(x);
    float s  = __builtin_amdgcn_sqrtf(fmaxf(0.f, 1.f - ax));
    float p  = fmaf(ax, fmaf(ax, fmaf(ax, -0.0187293f, 0.0742610f), -0.2121144f), 1.5707288f);
    float r  = s * p;
    return (x >= 0.f) ? r : 3.14159265358979f - r;
}

__device__ __forceinline__ float ang(float p2, float t2, float dot) {
    float inv = __builtin_amdgcn_rsqf(p2 * t2);   // raw v_rsq: 1 instr
    float c   = __builtin_amdgcn_fmed3f(dot * inv, -1.f, 1.f);
    return fast_acos(c);
}

// Shared-subexpression corner math: 8 diffs, 8 squares, 4 cross-products
// computed once; each box corner is 3 adds + ang().
__device__ __forceinline__ float dir_item(float4 L, float4 O, float4 Tn, bool first) {
    float pa = L.x + O.x, pb = L.y + O.y;
    float Px0 = pa - 0.5f * (L.z + O.z), Py0 = pb - 0.5f * (L.w + O.w);
    float Px1 = pa, Py1 = pb;
    float Tx0 = Tn.x - 0.5f * Tn.z, Ty0 = Tn.y - 0.5f * Tn.w;
    float Tx1 = Tn.x, Ty1 = Tn.y;
    float Lx1 = L.x - 0.5f * L.z, Ly1 = L.y - 0.5f * L.w;
    float Lx0, Ly0;
    if (first) { Lx0 = Lx1; Ly0 = Ly1; Lx1 = L.x; Ly1 = L.y; }
    else       { Lx0 = 0.5f * (L.x - L.z); Ly0 = 0.5f * (L.y - L.w); }

    float ax0 = Px0 - Lx0, ax1 = Px1 - Lx1, ay0 = Py0 - Ly0, ay1 = Py1 - Ly1;
    float bx0 = Tx0 - Lx0, bx1 = Tx1 - Lx1, by0 = Ty0 - Ly0, by1 = Ty1 - Ly1;
    float acx = 0.5f * (ax0 + ax1), acy = 0.5f * (ay0 + ay1);
    float bcx = 0.5f * (bx0 + bx1), bcy = 0.5f * (by0 + by1);
    float sax0 = ax0 * ax0, sax1 = ax1 * ax1, say0 = ay0 * ay0, say1 = ay1 * ay1;
    float sbx0 = bx0 * bx0, sbx1 = bx1 * bx1, sby0 = by0 * by0, sby1 = by1 * by1;
    float cx0 = ax0 * bx0, cx1 = ax1 * bx1, cy0 = ay0 * by0, cy1 = ay1 * by1;

    float acc;
    acc  = ang(fmaf(acx, acx, acy * acy), fmaf(bcx, bcx, bcy * bcy),
               fmaf(acx, bcx, acy * bcy));
    acc += ang(sax0 + say0, sbx0 + sby0, cx0 + cy0);
    acc += ang(sax0 + say1, sbx0 + sby1, cx0 + cy1);
    acc += ang(sax1 + say0, sbx1 + sby0, cx1 + cy0);
    acc += ang(sax1 + say1, sbx1 + sby1, cx1 + cy1);
    return acc;
}

__device__ __forceinline__ float sl1_4(float4 O, float4 D) {
    float s = 0.f;
    { float d = O.x - D.x, ad = fabsf(d); s += (ad < 1.f) ? 0.5f * d * d : ad - 0.5f; }
    { float d = O.y - D.y, ad = fabsf(d); s += (ad < 1.f) ? 0.5f * d * d : ad - 0.5f; }
    { float d = O.z - D.z, ad = fabsf(d); s += (ad < 1.f) ? 0.5f * d * d : ad - 0.5f; }
    { float d = O.w - D.w, ad = fabsf(d); s += (ad < 1.f) ? 0.5f * d * d : ad - 0.5f; }
    return s;
}

// One thread owns one p for 4 frames (grp g: t = 4g..4g+3). Fused sl1 + dir:
// every 32B targets record is consumed fully; t+1 rows reused in registers.
__global__ __launch_bounds__(BS)
void fused_kernel(const float* __restrict__ outputs,
                  const float* __restrict__ targets,
                  float* __restrict__ out,
                  float* __restrict__ partials,
                  int P, float w) {
    __shared__ float smem[BS / 64];
    long long gid = (long long)blockIdx.x * BS + threadIdx.x;
    float acc = 0.f;
    if (gid < 4ll * P) {
        int grp     = (int)(gid / P);          // 0..3
        long long p = gid - (long long)grp * P;
        const long long ts8 = 8ll * P, os4 = 4ll * P;
        const float* tb = targets + ((long long)(grp * 4) * P + p) * 8;
        const float* ob = outputs + ((long long)(grp * 4) * P + p) * 4;
        float*       wb = out + (long long)(grp * 4) * P + p;
        const bool has4 = (grp < 3);

        float4 Tf0 = LD4(tb);
        float4 Tf1 = LD4(tb + ts8);
        float4 Tf2 = LD4(tb + 2 * ts8);
        float4 Tf3 = LD4(tb + 3 * ts8);
        float4 Ts0 = LD4(tb + 4);
        float4 Ts1 = LD4(tb + ts8 + 4);
        float4 Ts2 = LD4(tb + 2 * ts8 + 4);
        float4 Ts3 = LD4(tb + 3 * ts8 + 4);
        float4 O0  = LD4(ob);
        float4 O1  = LD4(ob + os4);
        float4 O2  = LD4(ob + 2 * os4);
        float4 O3  = LD4(ob + 3 * os4);
        float4 Tf4 = has4 ? LD4(tb + 4 * ts8) : make_float4(0.f, 0.f, 0.f, 0.f);

        // smooth-L1 part (finalize adds the dir constant)
        wb[0]       = sl1_4(O0, Ts0) * w;
        wb[P]       = sl1_4(O1, Ts1) * w;
        wb[2ll * P] = sl1_4(O2, Ts2) * w;
        wb[3ll * P] = sl1_4(O3, Ts3) * w;

        acc  = dir_item(Tf0, O0, Tf1, grp == 0);
        acc += dir_item(Tf1, O1, Tf2, false);
        acc += dir_item(Tf2, O2, Tf3, false);
        if (has4) acc += dir_item(Tf3, O3, Tf4, false);
    }
    #pragma unroll
    for (int off = 32; off > 0; off >>= 1) acc += __shfl_down(acc, off, 64);
    int lane = threadIdx.x & 63, w64 = threadIdx.x >> 6;
    if (lane == 0) smem[w64] = acc;
    __syncthreads();
    if (threadIdx.x == 0) {
        float r = 0.f;
        #pragma unroll
        for (int i = 0; i < BS / 64; ++i) r += smem[i];
        partials[blockIdx.x] = r;
    }
}

__global__ void finalize_kernel(const float* __restrict__ partials, int nb,
                                float* __restrict__ out, long long n4, int P) {
    __shared__ double dsm[BS / 64];
    __shared__ float c_sh;
    double dacc = 0.0;
    for (int i = threadIdx.x; i < nb; i += BS) dacc += (double)partials[i];
    #pragma unroll
    for (int off = 32; off > 0; off >>= 1) dacc += __shfl_down(dacc, off, 64);
    int lane = threadIdx.x & 63, w = threadIdx.x >> 6;
    if (lane == 0) dsm[w] = dacc;
    __syncthreads();
    if (threadIdx.x == 0) {
        double tot = dsm[0] + dsm[1] + dsm[2] + dsm[3];
        c_sh = (float)(0.01 * 0.2 * tot / ((double)P * 15.0));
    }
    __syncthreads();
    float c = c_sh;

    float4* o4 = reinterpret_cast<float4*>(out);
    long long stride = (long long)gridDim.x * blockDim.x;
    for (long long i = (long long)blockIdx.x * blockDim.x + threadIdx.x; i < n4; i += stride) {
        float4 v = o4[i];
        v.x += c; v.y += c; v.z += c; v.w += c;
        o4[i] = v;
    }
}

extern "C" void kernel_launch(void* const* d_in, const int* in_sizes, int n_in,
                              void* d_out, int out_size, void* d_ws, size_t ws_size,
                              hipStream_t stream) {
    const float* outputs = (const float*)d_in[0];
    const float* targets = (const float*)d_in[1];
    float* out = (float*)d_out;
    float* partials = (float*)d_ws;

    const int T = 16;
    int P = in_sizes[0] / (T * 4);                 // 200000

    long long units = 4ll * P;                     // 800,000
    int nb1 = (int)((units + BS - 1) / BS);        // 3125 blocks

    fused_kernel<<<nb1, BS, 0, stream>>>(outputs, targets, out, partials,
                                         P, 0.99f / (float)P);

    long long n4 = (long long)out_size / 4;        // 16P/4
    int nb2 = (int)((n4 + BS - 1) / BS);
    if (nb2 > 2048) nb2 = 2048;
    finalize_kernel<<<nb2, BS, 0, stream>>>(partials, nb1, out, n4, P);
}